// Round 9
// baseline (99.840 us; speedup 1.0000x reference)
//
#include <hip/hip_runtime.h>

namespace {
constexpr int NB = 64;    // batches
constexpr int NS = 196;   // sites
constexpr int ND = 64;    // bond dim
constexpr int NO = 10;

// Layouts: x [B][S][2] ; cores [S][D][D][2] (site 32768B, row 512B) ; oc [O][D][D]
//
// R9: 4-wave cooperative chain. 128 blocks (block 2b+d = batch b, dir d) x 256 thr.
// Both chains as row-vector x matrix: out[c] = x0*sum_k v[k]*A0[k,c] + x1*sum_k v[k]*A1[k,c]
//   left  (d=0): A[k,c] = cores[s][k][c]     (k=row l, c=col r), sites 0..97
//   right (d=1): A[k,c] = cores[s][c][k]     (k=col r, c=row l), sites 195..98
// Wave w owns output cols c in [16w,16w+16): stages only ITS 8KB slab per site
// (8x global_load_lds dwordx4, per-lane src; LDS dst wave-uniform+lane*16).
// Lane (g=lane>>4, j=lane&15): col c=16w+j, k in [16g,16g+16): 32 FMA, reduce
// over g via 2x shfl_xor, lane g==0 writes vbuf[p^1][16w+j].
// Cross-wave sync: ping-pong vbuf + raw s_barrier (NO __syncthreads in loop --
// it would s_waitcnt vmcnt(0) and drain the pipeline). Per-wave counted
// vmcnt(16) (depth-3 ring x 8 loads), never 0 in-loop; drained epilogue.
// Loop has ZERO compiler-issued VMEM (x staged to LDS in prologue).

typedef const __attribute__((address_space(1))) void* gasp_t;
typedef __attribute__((address_space(3))) void* lasp_t;

#define SB0() __builtin_amdgcn_sched_barrier(0)
#define WAITV(N) do { asm volatile("s_waitcnt vmcnt(" #N ")" ::: "memory"); SB0(); } while (0)
#define LGKM0() do { asm volatile("s_waitcnt lgkmcnt(0)" ::: "memory"); SB0(); } while (0)
#define BARX()  do { asm volatile("s_barrier" ::: "memory"); } while (0)
#define GL2LDS(g, l) __builtin_amdgcn_global_load_lds((gasp_t)(g), (lasp_t)(l), 16, 0, 0)

// ---- stage left slab of site S into tiles[T][w]: cols 16w..16w+16, all 64 rows
// instr k: rows 8k..8k+8 (1KB); lane i: row 8k+(i>>3), 16B chunk (i&7) of the
// row's 128B col-slice. LDS: row-major 128B rows, 32B pad per 8 rows (1056B/instr).
#define LISSUE(T, S) do {                                                     \
  const float* _gp = cores + (size_t)(S) * 8192 + w * 32                      \
                     + (lane >> 3) * 128 + (lane & 7) * 4;                    \
  float* _lp = &tiles[T][w][0];                                               \
  _Pragma("unroll") for (int k = 0; k < 8; ++k)                               \
    GL2LDS(_gp + k * 1024, _lp + k * 264);                                    \
} while (0)

// ---- stage right slab (transposed gather): rows l=16w..16w+16, all 64 cols r
// element (p=r>>1, j=l-16w) = 16B cores[l][2p..2p+2][0..2]. instr k: p=4k..4k+4;
// lane i: l-idx = i&15, p-sub = i>>4. Same 1056B/instr LDS layout.
#define RISSUE(T, S) do {                                                     \
  const float* _gp = cores + (size_t)(S) * 8192                               \
                     + (16 * w + (lane & 15)) * 128 + (lane >> 4) * 4;        \
  float* _lp = &tiles[T][w][0];                                               \
  _Pragma("unroll") for (int k = 0; k < 8; ++k)                               \
    GL2LDS(_gp + k * 16, _lp + k * 264);                                      \
} while (0)

// ---- left compute: element (k=16g+t, j) = float2 at (2g+(t>>3))*264+(t&7)*32+2j
#define COMPL(T, P, XX, XY) do {                                              \
  const float* _sl = &tiles[T][w][0];                                         \
  const float4* _vb = (const float4*)(&vbuf[P][0]);                           \
  const float4 _v0 = _vb[4*g], _v1 = _vb[4*g+1];                              \
  const float4 _v2 = _vb[4*g+2], _v3 = _vb[4*g+3];                            \
  const float* _s0 = _sl + 2*g*264 + 2*j;                                     \
  const float* _s1 = _s0 + 264;                                               \
  float _a0=0.f,_b0=0.f,_a1=0.f,_b1=0.f; float2 _m;                           \
  _m = *(const float2*)(_s0+  0); _a0=fmaf(_v0.x,_m.x,_a0); _b0=fmaf(_v0.x,_m.y,_b0); \
  _m = *(const float2*)(_s0+ 32); _a1=fmaf(_v0.y,_m.x,_a1); _b1=fmaf(_v0.y,_m.y,_b1); \
  _m = *(const float2*)(_s0+ 64); _a0=fmaf(_v0.z,_m.x,_a0); _b0=fmaf(_v0.z,_m.y,_b0); \
  _m = *(const float2*)(_s0+ 96); _a1=fmaf(_v0.w,_m.x,_a1); _b1=fmaf(_v0.w,_m.y,_b1); \
  _m = *(const float2*)(_s0+128); _a0=fmaf(_v1.x,_m.x,_a0); _b0=fmaf(_v1.x,_m.y,_b0); \
  _m = *(const float2*)(_s0+160); _a1=fmaf(_v1.y,_m.x,_a1); _b1=fmaf(_v1.y,_m.y,_b1); \
  _m = *(const float2*)(_s0+192); _a0=fmaf(_v1.z,_m.x,_a0); _b0=fmaf(_v1.z,_m.y,_b0); \
  _m = *(const float2*)(_s0+224); _a1=fmaf(_v1.w,_m.x,_a1); _b1=fmaf(_v1.w,_m.y,_b1); \
  _m = *(const float2*)(_s1+  0); _a0=fmaf(_v2.x,_m.x,_a0); _b0=fmaf(_v2.x,_m.y,_b0); \
  _m = *(const float2*)(_s1+ 32); _a1=fmaf(_v2.y,_m.x,_a1); _b1=fmaf(_v2.y,_m.y,_b1); \
  _m = *(const float2*)(_s1+ 64); _a0=fmaf(_v2.z,_m.x,_a0); _b0=fmaf(_v2.z,_m.y,_b0); \
  _m = *(const float2*)(_s1+ 96); _a1=fmaf(_v2.w,_m.x,_a1); _b1=fmaf(_v2.w,_m.y,_b1); \
  _m = *(const float2*)(_s1+128); _a0=fmaf(_v3.x,_m.x,_a0); _b0=fmaf(_v3.x,_m.y,_b0); \
  _m = *(const float2*)(_s1+160); _a1=fmaf(_v3.y,_m.x,_a1); _b1=fmaf(_v3.y,_m.y,_b1); \
  _m = *(const float2*)(_s1+192); _a0=fmaf(_v3.z,_m.x,_a0); _b0=fmaf(_v3.z,_m.y,_b0); \
  _m = *(const float2*)(_s1+224); _a1=fmaf(_v3.w,_m.x,_a1); _b1=fmaf(_v3.w,_m.y,_b1); \
  float _y = fmaf((XX), _a0+_a1, (XY)*(_b0+_b1));                             \
  _y += __shfl_xor(_y, 16, 64);                                               \
  _y += __shfl_xor(_y, 32, 64);                                               \
  if (g == 0) vbuf[(P)^1][16*w + j] = _y;                                     \
} while (0)

// ---- right compute: b128 at (2g+(t>>3))*264 + ((t>>1)&3)*64 + 4j gives
// (c0,c1) for k=16g+t and k=16g+t+1
#define COMPR(T, P, XX, XY) do {                                              \
  const float* _sl = &tiles[T][w][0];                                         \
  const float4* _vb = (const float4*)(&vbuf[P][0]);                           \
  const float4 _v0 = _vb[4*g], _v1 = _vb[4*g+1];                              \
  const float4 _v2 = _vb[4*g+2], _v3 = _vb[4*g+3];                            \
  const float* _s0 = _sl + 2*g*264 + 4*j;                                     \
  const float* _s1 = _s0 + 264;                                               \
  float _a0=0.f,_b0=0.f,_a1=0.f,_b1=0.f; float4 _m;                           \
  _m = *(const float4*)(_s0+  0); _a0=fmaf(_v0.x,_m.x,_a0); _b0=fmaf(_v0.x,_m.y,_b0); \
                                  _a0=fmaf(_v0.y,_m.z,_a0); _b0=fmaf(_v0.y,_m.w,_b0); \
  _m = *(const float4*)(_s0+ 64); _a1=fmaf(_v0.z,_m.x,_a1); _b1=fmaf(_v0.z,_m.y,_b1); \
                                  _a1=fmaf(_v0.w,_m.z,_a1); _b1=fmaf(_v0.w,_m.w,_b1); \
  _m = *(const float4*)(_s0+128); _a0=fmaf(_v1.x,_m.x,_a0); _b0=fmaf(_v1.x,_m.y,_b0); \
                                  _a0=fmaf(_v1.y,_m.z,_a0); _b0=fmaf(_v1.y,_m.w,_b0); \
  _m = *(const float4*)(_s0+192); _a1=fmaf(_v1.z,_m.x,_a1); _b1=fmaf(_v1.z,_m.y,_b1); \
                                  _a1=fmaf(_v1.w,_m.z,_a1); _b1=fmaf(_v1.w,_m.w,_b1); \
  _m = *(const float4*)(_s1+  0); _a0=fmaf(_v2.x,_m.x,_a0); _b0=fmaf(_v2.x,_m.y,_b0); \
                                  _a0=fmaf(_v2.y,_m.z,_a0); _b0=fmaf(_v2.y,_m.w,_b0); \
  _m = *(const float4*)(_s1+ 64); _a1=fmaf(_v2.z,_m.x,_a1); _b1=fmaf(_v2.z,_m.y,_b1); \
                                  _a1=fmaf(_v2.w,_m.z,_a1); _b1=fmaf(_v2.w,_m.w,_b1); \
  _m = *(const float4*)(_s1+128); _a0=fmaf(_v3.x,_m.x,_a0); _b0=fmaf(_v3.x,_m.y,_b0); \
                                  _a0=fmaf(_v3.y,_m.z,_a0); _b0=fmaf(_v3.y,_m.w,_b0); \
  _m = *(const float4*)(_s1+192); _a1=fmaf(_v3.z,_m.x,_a1); _b1=fmaf(_v3.z,_m.y,_b1); \
                                  _a1=fmaf(_v3.w,_m.z,_a1); _b1=fmaf(_v3.w,_m.w,_b1); \
  float _y = fmaf((XX), _a0+_a1, (XY)*(_b0+_b1));                             \
  _y += __shfl_xor(_y, 16, 64);                                               \
  _y += __shfl_xor(_y, 32, 64);                                               \
  if (g == 0) vbuf[(P)^1][16*w + j] = _y;                                     \
} while (0)

// per-step macros: WAIT oldest tile -> COMP -> drain lds -> re-issue -> barrier
#define STEPL(T, TAU) do {                                                    \
  const float2 _xc = xp2[TAU];                                                \
  WAITV(16); COMPL(T, (TAU)&1, _xc.x, _xc.y); LGKM0();                        \
  LISSUE(T, ((TAU)+3 < 98) ? ((TAU)+3) : 97); BARX();                         \
} while (0)

#define STEPR(T, TAU) do {                                                    \
  const float2 _xc = xp2[195-(TAU)];                                          \
  WAITV(16); COMPR(T, (TAU)&1, _xc.x, _xc.y); LGKM0();                        \
  RISSUE(T, 195 - (((TAU)+3 < 98) ? ((TAU)+3) : 97)); BARX();                 \
} while (0)

__global__ __launch_bounds__(256, 1) void mps_chain_kernel(
    const float* __restrict__ x,      // [B][S][2]
    const float* __restrict__ cores,  // [S][D][D][2]
    float* __restrict__ ws)           // [B][2][64]
{
    __shared__ __align__(16) float tiles[3][4][2112];  // 3-ring x 4 waves x 8448B
    __shared__ __align__(16) float vbuf[2][ND];        // ping-pong vector
    __shared__ __align__(16) float xlds[NS * 2];

    const int bid   = blockIdx.x;
    const int batch = bid >> 1;
    const int right = bid & 1;
    const int tid   = threadIdx.x;
    const int w     = tid >> 6;
    const int lane  = tid & 63;
    const int g     = lane >> 4, j = lane & 15;

    for (int i = tid; i < 98; i += 256)
        ((float4*)xlds)[i] = ((const float4*)(x + batch * (NS * 2)))[i];
    if (tid < 64) vbuf[0][tid] = (tid == 0) ? 1.0f : 0.0f;
    __syncthreads();   // only full sync: drains prologue before asm pipeline
    const float2* xp2 = (const float2*)xlds;

    if (!right) {
        LISSUE(0, 0); LISSUE(1, 1); LISSUE(2, 2);
        for (int t6 = 0; t6 < 96; t6 += 6) {
            STEPL(0, t6 + 0); STEPL(1, t6 + 1); STEPL(2, t6 + 2);
            STEPL(0, t6 + 3); STEPL(1, t6 + 4); STEPL(2, t6 + 5);
        }
        { const float2 _xc = xp2[96];
          WAITV(16); COMPL(0, 0, _xc.x, _xc.y); LGKM0(); BARX(); }
        { const float2 _xc = xp2[97];
          WAITV(0);  COMPL(1, 1, _xc.x, _xc.y); LGKM0(); BARX(); }
    } else {
        RISSUE(0, 195); RISSUE(1, 194); RISSUE(2, 193);
        for (int t6 = 0; t6 < 96; t6 += 6) {
            STEPR(0, t6 + 0); STEPR(1, t6 + 1); STEPR(2, t6 + 2);
            STEPR(0, t6 + 3); STEPR(1, t6 + 4); STEPR(2, t6 + 5);
        }
        { const float2 _xc = xp2[99];
          WAITV(16); COMPR(0, 0, _xc.x, _xc.y); LGKM0(); BARX(); }
        { const float2 _xc = xp2[98];
          WAITV(0);  COMPR(1, 1, _xc.x, _xc.y); LGKM0(); BARX(); }
    }
    // all asm loads drained (WAITV(0) above); final vector in vbuf[0]
    if (tid < 64) ws[batch * 128 + right * 64 + tid] = vbuf[0][tid];
}

__global__ __launch_bounds__(128) void mps_out_kernel(
    const float* __restrict__ ws,     // [B][2][64]
    const float* __restrict__ oc,     // [O][D][D]
    float* __restrict__ out)          // [B][O]
{
    __shared__ __align__(16) float lsh[ND];
    __shared__ __align__(16) float rsh[ND];
    const int b    = blockIdx.x;
    const int tid  = threadIdx.x;
    const int wave = tid >> 6;
    const int lane = tid & 63;
    if (wave == 0) lsh[lane] = ws[b * 128 + lane];
    else           rsh[lane] = ws[b * 128 + 64 + lane];
    __syncthreads();

    #pragma unroll
    for (int oo = 0; oo < 5; ++oo) {
        const int o = wave * 5 + oo;
        const float* ocp = oc + o * (ND * ND) + lane * ND;
        float acc = 0.f;
        #pragma unroll
        for (int t = 0; t < ND; t += 4) {
            const float4 r4 = *(const float4*)(rsh + t);
            const float4 c4 = *(const float4*)(ocp + t);
            acc = fmaf(c4.x, r4.x, acc);
            acc = fmaf(c4.y, r4.y, acc);
            acc = fmaf(c4.z, r4.z, acc);
            acc = fmaf(c4.w, r4.w, acc);
        }
        float p = lsh[lane] * acc;
        #pragma unroll
        for (int off = 32; off > 0; off >>= 1) p += __shfl_xor(p, off, 64);
        if (lane == 0) out[b * NO + o] = p;
    }
}
} // namespace

extern "C" void kernel_launch(void* const* d_in, const int* in_sizes, int n_in,
                              void* d_out, int out_size, void* d_ws, size_t ws_size,
                              hipStream_t stream) {
    const float* x     = (const float*)d_in[0];
    const float* cores = (const float*)d_in[1];
    const float* ocp   = (const float*)d_in[2];
    float* out = (float*)d_out;
    float* ws  = (float*)d_ws;   // 64*128 floats = 32 KB
    hipLaunchKernelGGL(mps_chain_kernel, dim3(2 * NB), dim3(256), 0, stream, x, cores, ws);
    hipLaunchKernelGGL(mps_out_kernel,   dim3(NB),     dim3(128), 0, stream, ws, ocp, out);
}

// Round 12
// 91.749 us; speedup vs baseline: 1.0882x; 1.0882x over previous
//
#include <hip/hip_runtime.h>

namespace {
constexpr int NB = 64;    // batches
constexpr int NS = 196;   // sites
constexpr int ND = 64;    // bond dim
constexpr int NO = 10;

// Layouts: x [B][S][2] ; cores [S][D][D][2] (site 32768B, row 512B) ; oc [O][D][D]
//
// R12 = R8 (passed @99.7us) with ALL in-loop LDS accesses converted to inline
// asm (ds_read_b128/b64, ds_write_b64/b32). Staging stays the PROVEN builtin
// global_load_lds (R10/R11's asm DMA failed twice). With zero compiler-visible
// LDS ops in the loop, SIInsertWaitcnts has no ds_read to guard and cannot
// insert its conservative s_waitcnt vmcnt(0) (the suspected R6-R9 per-step
// full-pipeline drain). Only our counted WAITV(63) remains (depth-3 ring,
// 96 loads in flight, never 0 in-loop); drained epilogue; asm reads cannot
// be undef-folded (R10 failure mode). Address math byte-identical to R8.

typedef float f32x4 __attribute__((ext_vector_type(4)));
typedef float f32x2 __attribute__((ext_vector_type(2)));

typedef const __attribute__((address_space(1))) void* gasp_t;
typedef __attribute__((address_space(3))) void* lasp_t;
typedef __attribute__((address_space(3))) float* lfp_t;

#define LDSOFF(p) ((unsigned)(unsigned long long)(lfp_t)(p))
#define SB0() __builtin_amdgcn_sched_barrier(0)
#define WAITV(N) do { asm volatile("s_waitcnt vmcnt(" #N ")" ::: "memory"); SB0(); } while (0)
#define LGKM0() do { asm volatile("s_waitcnt lgkmcnt(0)" ::: "memory"); SB0(); } while (0)
#define GL2LDS(g, l) __builtin_amdgcn_global_load_lds((gasp_t)(g), (lasp_t)(l), 16, 0, 0)

#define RD4(d, b, off) asm volatile("ds_read_b128 %0, %1 offset:%c2" : "=v"(d) : "v"(b), "i"(off))
#define RD2(d, b, off) asm volatile("ds_read_b64 %0, %1 offset:%c2"  : "=v"(d) : "v"(b), "i"(off))
#define RD1(d, b)      asm volatile("ds_read_b32 %0, %1"             : "=v"(d) : "v"(b))
#define WR2(b, v2)     asm volatile("ds_write_b64 %0, %1" :: "v"(b), "v"(v2))
#define WR1(b, v1)     asm volatile("ds_write_b32 %0, %1" :: "v"(b), "v"(v1))

#define REP8(M, B) M(B) M((B)+1) M((B)+2) M((B)+3) M((B)+4) M((B)+5) M((B)+6) M((B)+7)
#define REP16(M) REP8(M, 0) REP8(M, 8)
#define REP32(M) REP8(M, 0) REP8(M, 8) REP8(M, 16) REP8(M, 24)

// ---- staging (verbatim R8, builtin) ----
#define LISSUE(T, S) do {                                                     \
  const float* _g = cores + (size_t)(S) * 8192 + lane * 4;                    \
  float* _l = &tile[T][0];                                                    \
  _Pragma("unroll") for (int i = 0; i < 32; ++i)                              \
    GL2LDS(_g + i * 256, _l + i * 256);                                       \
} while (0)

#define RISSUE(T, S) do {                                                     \
  const float* _g = cores + (size_t)(S) * 8192;                               \
  float* _l = &tile[T][0];                                                    \
  _Pragma("unroll") for (int k = 0; k < 32; ++k)                              \
    GL2LDS(_g + k * 256 + roff[k & 3], _l + k * 256);                         \
} while (0)

// ---- left compute: lane (h,j) -> cols 2j,2j+1, rows 32h..32h+31 ----
#define LVRD(u) RD4(vv[u], vbl, (u) * 16);
#define LTRD(i) RD4(tt[i], lb, (i) * 512);
#define LFMA(i) { const float vl = vv[(i) >> 2][(i) & 3];                     \
  axx[((i) >> 2) & 1] = fmaf(vl, tt[i].x, axx[((i) >> 2) & 1]);               \
  ayy[((i) >> 2) & 1] = fmaf(vl, tt[i].y, ayy[((i) >> 2) & 1]);               \
  azz[((i) >> 2) & 1] = fmaf(vl, tt[i].z, azz[((i) >> 2) & 1]);               \
  aww[((i) >> 2) & 1] = fmaf(vl, tt[i].w, aww[((i) >> 2) & 1]); }

#define LCOMP(LBV, X0, X1) do {                                               \
  const unsigned lb = (LBV);                                                  \
  f32x4 tt[32]; f32x4 vv[8];                                                  \
  REP8(LVRD, 0)                                                               \
  REP32(LTRD)                                                                 \
  LGKM0();                                                                    \
  float axx[2] = {0, 0}, ayy[2] = {0, 0}, azz[2] = {0, 0}, aww[2] = {0, 0};   \
  REP32(LFMA)                                                                 \
  float y0 = fmaf((X0), axx[0] + axx[1], (X1) * (ayy[0] + ayy[1]));           \
  float y1 = fmaf((X0), azz[0] + azz[1], (X1) * (aww[0] + aww[1]));           \
  y0 += __shfl_xor(y0, 32, 64);                                               \
  y1 += __shfl_xor(y1, 32, 64);                                               \
  if (h == 0) { f32x2 yy; yy.x = y0; yy.y = y1; WR2(vwl, yy); }               \
  SB0();                                                                      \
} while (0)

// ---- right compute: lane = row l; swizzled granule reads (byte math = R8) ----
#define RVRD(u) RD4(vv[u], vB, (u) * 16);
#define RTRD0(t) RD4(qq[t], rbA[(t) & 7], ((t) >> 3) * 128);
#define RTRD1(t) RD4(qq[t], rbA[(t) & 7], 32768 + ((t) >> 3) * 128);
#define RFMA(t) { const float v0 = vv[(t) >> 1][((t) & 1) * 2];               \
                  const float v1 = vv[(t) >> 1][((t) & 1) * 2 + 1];           \
  aA[(t) & 3] = fmaf(v0, qq[t].x, aA[(t) & 3]);                               \
  bA[(t) & 3] = fmaf(v0, qq[t].y, bA[(t) & 3]);                               \
  aB[(t) & 3] = fmaf(v1, qq[t].z, aB[(t) & 3]);                               \
  bB[(t) & 3] = fmaf(v1, qq[t].w, bB[(t) & 3]); }

#define RCOMP(RBARR, RDM, X0, X1) do {                                        \
  const unsigned* rbA = (RBARR);                                              \
  f32x4 qq[32]; f32x4 vv[16];                                                 \
  REP16(RVRD)                                                                 \
  REP32(RDM)                                                                  \
  LGKM0();                                                                    \
  float aA[4] = {0,0,0,0}, bA[4] = {0,0,0,0};                                 \
  float aB[4] = {0,0,0,0}, bB[4] = {0,0,0,0};                                 \
  REP32(RFMA)                                                                 \
  const float s0 = ((aA[0]+aA[1])+(aA[2]+aA[3])) + ((aB[0]+aB[1])+(aB[2]+aB[3])); \
  const float s1 = ((bA[0]+bA[1])+(bA[2]+bA[3])) + ((bB[0]+bB[1])+(bB[2]+bB[3])); \
  const float yn = fmaf((X0), s0, (X1) * s1);                                 \
  WR1(vwr, yn);                                                               \
  SB0();                                                                      \
} while (0)

__global__ __launch_bounds__(64, 1) void mps_chain_kernel(
    const float* __restrict__ x,      // [B][S][2]
    const float* __restrict__ cores,  // [S][D][D][2]
    float* __restrict__ ws)           // [B][2][64]
{
    __shared__ __align__(16) float tile[3][8192];   // 96KB ring -> 1 block/CU
    __shared__ __align__(16) float vbuf[ND];
    __shared__ __align__(16) float xlds[NS * 2];

    const int bid   = blockIdx.x;
    const int batch = bid >> 1;
    const int right = bid & 1;
    const int lane  = threadIdx.x;

    // prologue: stage x[batch] + init vbuf with VISIBLE ops, then barrier
    // (drains vmcnt/lgkmcnt -> our asm counters start at 0)
    #pragma unroll
    for (int i = lane; i < 98; i += 64)
        ((float4*)xlds)[i] = ((const float4*)(x + batch * (NS * 2)))[i];
    vbuf[lane] = (lane == 0) ? 1.0f : 0.0f;
    __syncthreads();

    const unsigned tb0 = LDSOFF(&tile[0][0]);
    const unsigned vB  = LDSOFF(&vbuf[0]);
    const unsigned xB  = LDSOFF(&xlds[0]);

    if (!right) {
        const int h = lane >> 5, j = lane & 31;
        const unsigned lb0 = tb0 + (unsigned)(h * 16384 + j * 16);
        const unsigned lb1 = lb0 + 32768u, lb2 = lb0 + 65536u;
        const unsigned vbl = vB + (unsigned)(h * 128);
        const unsigned vwl = vB + (unsigned)(8 * j);
        LISSUE(0, 0); LISSUE(1, 1); LISSUE(2, 2);
        for (int s = 0; s < 96; s += 3) {
            const unsigned xo = xB + 8u * (unsigned)s;
            f32x2 xa, xb2, xc;
            RD2(xa, xo, 0); RD2(xb2, xo, 8); RD2(xc, xo, 16);
            WAITV(63); LCOMP(lb0, xa.x,  xa.y);  LISSUE(0, s + 3);
            WAITV(63); LCOMP(lb1, xb2.x, xb2.y); LISSUE(1, (s + 4 < 98) ? s + 4 : 97);
            WAITV(63); LCOMP(lb2, xc.x,  xc.y);  LISSUE(2, (s + 5 < 98) ? s + 5 : 97);
        }
        {
            const unsigned xo = xB + 8u * 96u;
            f32x2 xa, xb2;
            RD2(xa, xo, 0); RD2(xb2, xo, 8);
            WAITV(63); LCOMP(lb0, xa.x,  xa.y);     // site 96
            WAITV(0);  LCOMP(lb1, xb2.x, xb2.y);    // site 97 — fully drained
        }
        float fin; RD1(fin, vB + (unsigned)(lane * 4)); LGKM0();
        ws[batch * 128 + lane] = fin;
    } else {
        const int p7 = lane & 7;
        const int h2 = lane >> 5, j2 = lane & 31;
        int roff[4];
        #pragma unroll
        for (int m4 = 0; m4 < 4; ++m4)
            roff[m4] = h2 * 128 + ((j2 >> 3) << 5) + (((j2 & 7) ^ (2 * m4 + h2)) << 2);
        unsigned rb0[8], rb2[8];
        #pragma unroll
        for (int m = 0; m < 8; ++m) {
            rb0[m] = tb0 + (unsigned)(lane * 512) + (unsigned)(((m ^ p7)) << 4);
            rb2[m] = rb0[m] + 65536u;
        }
        const unsigned vwr = vB + (unsigned)(lane * 4);
        RISSUE(0, 195); RISSUE(1, 194); RISSUE(2, 193);
        for (int k = 0; k < 96; k += 3) {
            const unsigned xo = xB + 8u * (unsigned)(193 - k);
            f32x2 xa, xb2, xc;
            RD2(xa, xo, 16); RD2(xb2, xo, 8); RD2(xc, xo, 0);
            WAITV(63); RCOMP(rb0, RTRD0, xa.x,  xa.y);  RISSUE(0, 192 - k);
            WAITV(63); RCOMP(rb0, RTRD1, xb2.x, xb2.y); RISSUE(1, (191 - k > 98) ? 191 - k : 98);
            WAITV(63); RCOMP(rb2, RTRD0, xc.x,  xc.y);  RISSUE(2, (190 - k > 98) ? 190 - k : 98);
        }
        {
            const unsigned xo = xB + 8u * 98u;
            f32x2 x98, x99;
            RD2(x98, xo, 0); RD2(x99, xo, 8);
            WAITV(63); RCOMP(rb0, RTRD0, x99.x, x99.y);  // site 99
            WAITV(0);  RCOMP(rb0, RTRD1, x98.x, x98.y);  // site 98 — fully drained
        }
        float fin; RD1(fin, vB + (unsigned)(lane * 4)); LGKM0();
        ws[batch * 128 + 64 + lane] = fin;
    }
}

__global__ __launch_bounds__(128) void mps_out_kernel(
    const float* __restrict__ ws,     // [B][2][64]
    const float* __restrict__ oc,     // [O][D][D]
    float* __restrict__ out)          // [B][O]
{
    __shared__ __align__(16) float lsh[ND];
    __shared__ __align__(16) float rsh[ND];
    const int b    = blockIdx.x;
    const int tid  = threadIdx.x;
    const int wave = tid >> 6;
    const int lane = tid & 63;
    if (wave == 0) lsh[lane] = ws[b * 128 + lane];
    else           rsh[lane] = ws[b * 128 + 64 + lane];
    __syncthreads();

    #pragma unroll
    for (int oo = 0; oo < 5; ++oo) {
        const int o = wave * 5 + oo;
        const float* ocp = oc + o * (ND * ND) + lane * ND;
        float acc = 0.f;
        #pragma unroll
        for (int t = 0; t < ND; t += 4) {
            const float4 r4 = *(const float4*)(rsh + t);
            const float4 c4 = *(const float4*)(ocp + t);
            acc = fmaf(c4.x, r4.x, acc);
            acc = fmaf(c4.y, r4.y, acc);
            acc = fmaf(c4.z, r4.z, acc);
            acc = fmaf(c4.w, r4.w, acc);
        }
        float p = lsh[lane] * acc;
        #pragma unroll
        for (int off = 32; off > 0; off >>= 1) p += __shfl_xor(p, off, 64);
        if (lane == 0) out[b * NO + o] = p;
    }
}
} // namespace

extern "C" void kernel_launch(void* const* d_in, const int* in_sizes, int n_in,
                              void* d_out, int out_size, void* d_ws, size_t ws_size,
                              hipStream_t stream) {
    const float* x     = (const float*)d_in[0];
    const float* cores = (const float*)d_in[1];
    const float* ocp   = (const float*)d_in[2];
    float* out = (float*)d_out;
    float* ws  = (float*)d_ws;   // 64*128 floats = 32 KB
    hipLaunchKernelGGL(mps_chain_kernel, dim3(2 * NB), dim3(64), 0, stream, x, cores, ws);
    hipLaunchKernelGGL(mps_out_kernel,   dim3(NB),     dim3(128), 0, stream, ws, ocp, out);
}

// Round 14
// 90.663 us; speedup vs baseline: 1.1012x; 1.0120x over previous
//
#include <hip/hip_runtime.h>

namespace {
constexpr int NB = 64;    // batches
constexpr int NS = 196;   // sites
constexpr int ND = 64;    // bond dim
constexpr int NO = 10;
constexpr int EPAIRS = NS * ND * ND;            // 802816 (e0,e1) pairs
constexpr size_t EBYTES = (size_t)EPAIRS * 4;   // bf16 pair table: 3,211,264 B

// R14: cores = I + E. Pre-pass converts E = cores - I to BF16 pairs in d_ws
// ([s][l][r] order, 4B per (e0,e1) pair, e0 in LOW 16 bits; site 16384B,
// row 256B). bf16 = fp32 exponent range -> NO underflow (R13's fp16 u went
// subnormal because |v| ~ prod(x0+x1) ~ 1e-5..1e-7 and was flushed).
// Step: v'[c] = s*v[c] + x0*A0[c] + x1*A1[c],  A_i[c] = sum_l v[l]*E_i[l,c],
// with v pure fp32 (LDS + registers); only E is quantized (|E|<=0.06,
// rel err 2^-8 -> ~0.2% total chain error vs 2% threshold).
// Pipeline skeleton = R12/R13 (proven): depth-3 LDS ring (3x16KB), builtin
// global_load_lds staging (16x 1KB per site), counted s_waitcnt vmcnt(32),
// all in-loop LDS ops inline asm, drained epilogue, zero compiler VMEM in loop.

typedef unsigned u32x4 __attribute__((ext_vector_type(4)));
typedef float f32x4v __attribute__((ext_vector_type(4)));
typedef float f32x2v __attribute__((ext_vector_type(2)));

typedef const __attribute__((address_space(1))) void* gasp_t;
typedef __attribute__((address_space(3))) void* lasp_t;
typedef __attribute__((address_space(3))) char* lcp_t;

#define LDSOFF(p) ((unsigned)(unsigned long long)(lcp_t)(void*)(p))
#define SB0() __builtin_amdgcn_sched_barrier(0)
#define WAITV(N) do { asm volatile("s_waitcnt vmcnt(" #N ")" ::: "memory"); SB0(); } while (0)
#define LGKM0() do { asm volatile("s_waitcnt lgkmcnt(0)" ::: "memory"); SB0(); } while (0)
#define GL2LDS(g, l) __builtin_amdgcn_global_load_lds((gasp_t)(const void*)(g), (lasp_t)(void*)(l), 16, 0, 0)

#define RD4(d, b, off) asm volatile("ds_read_b128 %0, %1 offset:%c2" : "=v"(d) : "v"(b), "i"(off))
#define RD2R(d, a)     asm volatile("ds_read_b64 %0, %1"             : "=v"(d) : "v"(a))
#define WR4(b, v4)     asm volatile("ds_write_b128 %0, %1" :: "v"(b), "v"(v4))
#define WR1(b, v1)     asm volatile("ds_write_b32 %0, %1" :: "v"(b), "v"(v1))

// bf16 unpack: e0 = low 16 bits, e1 = high 16 bits
#define U0(w) __builtin_bit_cast(float, (unsigned)((w) << 16))
#define U1(w) __builtin_bit_cast(float, (unsigned)((w) & 0xFFFF0000u))

#define REP16(M) M(0) M(1) M(2) M(3) M(4) M(5) M(6) M(7) M(8) M(9) M(10) M(11) M(12) M(13) M(14) M(15)

// ---- staging: site tile = 16KB, 16x global_load_lds dwordx4 (1KB each) ----
// left: linear copy (row-major, row = 256B)
#define LISSUE(TOFF, S) do {                                                  \
  const char* _g = etab + (size_t)(S) * 16384 + lane * 16;                    \
  char* _l = tbc + (TOFF);                                                    \
  _Pragma("unroll") for (int i5 = 0; i5 < 16; ++i5)                           \
    GL2LDS(_g + i5 * 1024, _l + i5 * 1024);                                   \
} while (0)

// right: XOR-swizzled granules via pre-permuted SOURCE (rule #21).
// Physical granule gg of LDS row L holds logical granule (gg&8)|((gg&7)^(L&7)).
#define RISSUE(TOFF, S) do {                                                  \
  const char* _g = etab + (size_t)(S) * 16384;                                \
  char* _l = tbc + (TOFF);                                                    \
  _Pragma("unroll") for (int k5 = 0; k5 < 16; ++k5)                           \
    GL2LDS(_g + k5 * 1024 + vr[k5 & 1], _l + k5 * 1024);                      \
} while (0)

// ---- left compute: lane (q=lane>>4, t=lane&15) -> cols 4t..4t+3, rows 16q..16q+15
#define LT(i) RD4(tt[i], lbL, (TOFF_) + (i) * 256);
#define LF(i) { const float vi = vv[(i) >> 2][(i) & 3];                       \
  { const unsigned w = tt[i][0]; a00 = fmaf(vi, U0(w), a00); a10 = fmaf(vi, U1(w), a10); } \
  { const unsigned w = tt[i][1]; a01 = fmaf(vi, U0(w), a01); a11 = fmaf(vi, U1(w), a11); } \
  { const unsigned w = tt[i][2]; a02 = fmaf(vi, U0(w), a02); a12 = fmaf(vi, U1(w), a12); } \
  { const unsigned w = tt[i][3]; a03 = fmaf(vi, U0(w), a03); a13 = fmaf(vi, U1(w), a13); } }

#define LCOMP(TOFF, XC) do {                                                  \
  constexpr int TOFF_ = (TOFF);                                               \
  u32x4 tt[16]; f32x4v vv[4];                                                 \
  RD4(vv[0], vlB, 0); RD4(vv[1], vlB, 16);                                    \
  RD4(vv[2], vlB, 32); RD4(vv[3], vlB, 48);                                   \
  REP16(LT)                                                                   \
  LGKM0();                                                                    \
  float a00 = 0.f, a01 = 0.f, a02 = 0.f, a03 = 0.f;                           \
  float a10 = 0.f, a11 = 0.f, a12 = 0.f, a13 = 0.f;                           \
  REP16(LF)                                                                   \
  a00 += __shfl_xor(a00, 16, 64); a00 += __shfl_xor(a00, 32, 64);             \
  a01 += __shfl_xor(a01, 16, 64); a01 += __shfl_xor(a01, 32, 64);             \
  a02 += __shfl_xor(a02, 16, 64); a02 += __shfl_xor(a02, 32, 64);             \
  a03 += __shfl_xor(a03, 16, 64); a03 += __shfl_xor(a03, 32, 64);             \
  a10 += __shfl_xor(a10, 16, 64); a10 += __shfl_xor(a10, 32, 64);             \
  a11 += __shfl_xor(a11, 16, 64); a11 += __shfl_xor(a11, 32, 64);             \
  a12 += __shfl_xor(a12, 16, 64); a12 += __shfl_xor(a12, 32, 64);             \
  a13 += __shfl_xor(a13, 16, 64); a13 += __shfl_xor(a13, 32, 64);             \
  const float s0_ = (XC).x + (XC).y;                                          \
  y0 = fmaf(s0_, y0, fmaf((XC).x, a00, (XC).y * a10));                        \
  y1 = fmaf(s0_, y1, fmaf((XC).x, a01, (XC).y * a11));                        \
  y2 = fmaf(s0_, y2, fmaf((XC).x, a02, (XC).y * a12));                        \
  y3 = fmaf(s0_, y3, fmaf((XC).x, a03, (XC).y * a13));                        \
  if (q == 0) { f32x4v yv_; yv_[0] = y0; yv_[1] = y1; yv_[2] = y2;            \
                yv_[3] = y3; WR4(vwL, yv_); }                                 \
  SB0();                                                                      \
} while (0)

// ---- right compute: lane = row l; swizzled logical-granule reads ----
#define RU(m) RD4(vv[m], vB, (m) * 16);
#define RT(g) RD4(tt[g], rbR[(g) & 7], (TOFF_) + (((g) & 8) ? 128 : 0));
#define RF(g) {                                                               \
  { const unsigned w = tt[g][0]; const float vr_ = vv[g][0];                  \
    a00 = fmaf(vr_, U0(w), a00); a10 = fmaf(vr_, U1(w), a10); }               \
  { const unsigned w = tt[g][1]; const float vr_ = vv[g][1];                  \
    a01 = fmaf(vr_, U0(w), a01); a11 = fmaf(vr_, U1(w), a11); }               \
  { const unsigned w = tt[g][2]; const float vr_ = vv[g][2];                  \
    a02 = fmaf(vr_, U0(w), a02); a12 = fmaf(vr_, U1(w), a12); }               \
  { const unsigned w = tt[g][3]; const float vr_ = vv[g][3];                  \
    a03 = fmaf(vr_, U0(w), a03); a13 = fmaf(vr_, U1(w), a13); } }

#define RCOMP(TOFF, XC) do {                                                  \
  constexpr int TOFF_ = (TOFF);                                               \
  u32x4 tt[16]; f32x4v vv[16];                                                \
  REP16(RU)                                                                   \
  REP16(RT)                                                                   \
  LGKM0();                                                                    \
  float a00 = 0.f, a01 = 0.f, a02 = 0.f, a03 = 0.f;                           \
  float a10 = 0.f, a11 = 0.f, a12 = 0.f, a13 = 0.f;                           \
  REP16(RF)                                                                   \
  const float s0_ = (XC).x + (XC).y;                                          \
  yr = fmaf(s0_, yr, fmaf((XC).x, (a00 + a01) + (a02 + a03),                  \
                          (XC).y * ((a10 + a11) + (a12 + a13))));             \
  WR1(vwR, yr);                                                               \
  SB0();                                                                      \
} while (0)

__device__ __forceinline__ unsigned bf16rne(float f) {
    const unsigned b = __builtin_bit_cast(unsigned, f);
    return (b + 0x7FFFu + ((b >> 16) & 1u)) >> 16;
}

__global__ __launch_bounds__(256) void mps_conv_kernel(
    const float* __restrict__ cores, char* __restrict__ etab)
{
    const int p = blockIdx.x * 256 + threadIdx.x;   // pair index; grid covers exactly
    const int rem = p & 4095;
    const int l = rem >> 6, r = rem & 63;
    const float2 c = ((const float2*)cores)[p];
    const float sub = (l == r) ? 1.0f : 0.0f;
    const unsigned lo = bf16rne(c.x - sub);
    const unsigned hi = bf16rne(c.y - sub);
    ((unsigned*)etab)[p] = lo | (hi << 16);
}

__global__ __launch_bounds__(64, 1) void mps_chain_kernel(
    const float* __restrict__ x,      // [B][S][2]
    const char* __restrict__ etab,    // bf16 E table
    float* __restrict__ wsv)          // [B][2][64]
{
    __shared__ __align__(16) char tilebuf[3 * 16384];   // 48KB ring
    __shared__ __align__(16) float vbuf[ND];            // fp32 chain vector
    __shared__ __align__(16) float xlds[NS * 2];

    const int bid   = blockIdx.x;
    const int batch = bid >> 1;
    const int right = bid & 1;
    const int lane  = threadIdx.x;

    #pragma unroll
    for (int i = lane; i < 98; i += 64)
        ((float4*)xlds)[i] = ((const float4*)(x + batch * (NS * 2)))[i];
    vbuf[lane] = (lane == 0) ? 1.0f : 0.0f;
    __syncthreads();   // drains prologue: asm counters start at 0

    char* tbc = (char*)tilebuf;
    const unsigned tB = LDSOFF(tilebuf);
    const unsigned vB = LDSOFF(vbuf);
    const unsigned xB = LDSOFF(xlds);

    if (!right) {
        const int q = lane >> 4, t = lane & 15;
        const unsigned lbL = tB + (unsigned)(q * 4096 + t * 16);
        const unsigned vlB = vB + (unsigned)(q * 64);
        const unsigned vwL = vB + (unsigned)(t * 16);
        float y0 = (t == 0) ? 1.f : 0.f, y1 = 0.f, y2 = 0.f, y3 = 0.f;
        LISSUE(0, 0); LISSUE(16384, 1); LISSUE(32768, 2);
        f32x2v xc;
        for (int s = 0; s < 96; s += 3) {
            RD2R(xc, xB + 8u * (unsigned)s);
            WAITV(32); LCOMP(0, xc);     LISSUE(0, s + 3);
            RD2R(xc, xB + 8u * (unsigned)(s + 1));
            WAITV(32); LCOMP(16384, xc); LISSUE(16384, s + 4);
            RD2R(xc, xB + 8u * (unsigned)(s + 2));
            WAITV(32); LCOMP(32768, xc);
            LISSUE(32768, (s + 5 <= 97) ? (s + 5) : 97);
        }
        RD2R(xc, xB + 8u * 96u); WAITV(32); LCOMP(0, xc);       // site 96
        RD2R(xc, xB + 8u * 97u); WAITV(16); LCOMP(16384, xc);   // site 97
        WAITV(0); LGKM0();                                      // fully drained
        if (q == 0)
            ((float4*)(wsv + batch * 128))[t] = make_float4(y0, y1, y2, y3);
    } else {
        const int l7 = lane & 7;
        unsigned vr[2];
        {
            const int rw = lane >> 4, gg = lane & 15;
            #pragma unroll
            for (int par = 0; par < 2; ++par) {
                const int lz = (4 * par + rw) & 7;           // = row&7 for this instr parity
                const int g  = (gg & 8) | ((gg & 7) ^ lz);
                vr[par] = (unsigned)(rw * 256 + g * 16);
            }
        }
        unsigned rbR[8];
        #pragma unroll
        for (int m = 0; m < 8; ++m)
            rbR[m] = tB + (unsigned)(lane * 256 + ((m ^ l7) << 4));
        const unsigned vwR = vB + (unsigned)(lane * 4);
        float yr = (lane == 0) ? 1.f : 0.f;
        RISSUE(0, 195); RISSUE(16384, 194); RISSUE(32768, 193);
        f32x2v xc;
        for (int k = 0; k < 96; k += 3) {
            RD2R(xc, xB + 8u * (unsigned)(195 - k));
            WAITV(32); RCOMP(0, xc);     RISSUE(0, 192 - k);
            RD2R(xc, xB + 8u * (unsigned)(194 - k));
            WAITV(32); RCOMP(16384, xc); RISSUE(16384, 191 - k);
            RD2R(xc, xB + 8u * (unsigned)(193 - k));
            WAITV(32); RCOMP(32768, xc);
            RISSUE(32768, (k + 5 <= 97) ? (190 - k) : 98);
        }
        RD2R(xc, xB + 8u * 99u); WAITV(32); RCOMP(0, xc);       // site 99
        RD2R(xc, xB + 8u * 98u); WAITV(16); RCOMP(16384, xc);   // site 98
        WAITV(0); LGKM0();                                      // fully drained
        wsv[batch * 128 + 64 + lane] = yr;
    }
}

__global__ __launch_bounds__(128) void mps_out_kernel(
    const float* __restrict__ wsv,    // [B][2][64]
    const float* __restrict__ oc,     // [O][D][D]
    float* __restrict__ out)          // [B][O]
{
    __shared__ __align__(16) float lsh[ND];
    __shared__ __align__(16) float rsh[ND];
    const int b    = blockIdx.x;
    const int tid  = threadIdx.x;
    const int wave = tid >> 6;
    const int lane = tid & 63;
    if (wave == 0) lsh[lane] = wsv[b * 128 + lane];
    else           rsh[lane] = wsv[b * 128 + 64 + lane];
    __syncthreads();

    #pragma unroll
    for (int oo = 0; oo < 5; ++oo) {
        const int o = wave * 5 + oo;
        const float* ocp = oc + o * (ND * ND) + lane * ND;
        float acc = 0.f;
        #pragma unroll
        for (int t = 0; t < ND; t += 4) {
            const float4 r4 = *(const float4*)(rsh + t);
            const float4 c4 = *(const float4*)(ocp + t);
            acc = fmaf(c4.x, r4.x, acc);
            acc = fmaf(c4.y, r4.y, acc);
            acc = fmaf(c4.z, r4.z, acc);
            acc = fmaf(c4.w, r4.w, acc);
        }
        float p = lsh[lane] * acc;
        #pragma unroll
        for (int off = 32; off > 0; off >>= 1) p += __shfl_xor(p, off, 64);
        if (lane == 0) out[b * NO + o] = p;
    }
}
} // namespace

extern "C" void kernel_launch(void* const* d_in, const int* in_sizes, int n_in,
                              void* d_out, int out_size, void* d_ws, size_t ws_size,
                              hipStream_t stream) {
    const float* x     = (const float*)d_in[0];
    const float* cores = (const float*)d_in[1];
    const float* ocp   = (const float*)d_in[2];
    float* out = (float*)d_out;
    char*  etab = (char*)d_ws;                       // 3.2MB bf16 E table
    float* wsv  = (float*)((char*)d_ws + EBYTES);    // + 32KB chain vectors
    hipLaunchKernelGGL(mps_conv_kernel,  dim3(EPAIRS / 256), dim3(256), 0, stream, cores, etab);
    hipLaunchKernelGGL(mps_chain_kernel, dim3(2 * NB), dim3(64),  0, stream, x, etab, wsv);
    hipLaunchKernelGGL(mps_out_kernel,   dim3(NB),     dim3(128), 0, stream, wsv, ocp, out);
}

// Round 15
// 72.068 us; speedup vs baseline: 1.3854x; 1.2580x over previous
//
#include <hip/hip_runtime.h>

namespace {
constexpr int NB = 64, NS = 196, ND = 64, NO = 10;
constexpr int EPAIRS = NS * ND * ND;            // 802816 (e0,e1) pairs
constexpr size_t EBYTES = (size_t)EPAIRS * 4;   // bf16 pair table

// R15: 2-wave split chain, depth-6 per-wave DMA pipeline.
// etab: [s][l][r] bf16 pair (e0|e1<<16), site 16384B, row 256B.
// Left block: v'[c] = s*v[c] + x0*A0[c] + x1*A1[c], A_i[c] = sum_l v[l]E_i[l,c].
//   wave w owns cols [32w,32w+32): half-tile = cols half of every row (128B/row).
//   LDS half-tile [64][128B], swizzle: LDS(l,b) holds global half-row byte
//   b ^ ((l&7)<<4)  (pre-swizzled source; 16B-chunk-contiguous).
//   lane (q=lane>>4,t=lane&15): cc=2t,2t+1, l in [16q,16q+16), reduce over q.
// Right block: w'[l] = s*w[l] + sum_r (x0 E0[l,r] + x1 E1[l,r]) w[r].
//   wave w owns rows [32w,32w+32): half-tile = 32 full rows (256B each).
//   LDS(l_loc, granule G) holds global granule G ^ (l_loc&7) (16B granules).
//   lane: l_loc=lane>>1, h=lane&1 covers r in [32h,32h+32); reduce over pair.
// Pipeline: per wave 6-slot ring of 8KB half-tiles, 8 gload_lds each ->
// 48 outstanding (<=63 cap), counted WAITV(40) in loop, literal drains in tail.
// Cross-wave: vbuf[2] ping-pong (read parity P, write P^1) + one raw s_barrier
// per step. All in-loop LDS ops are inline asm (no compiler waitcnt injection).

typedef unsigned u32x4 __attribute__((ext_vector_type(4)));
typedef unsigned u32x2 __attribute__((ext_vector_type(2)));
typedef float f32x4v __attribute__((ext_vector_type(4)));
typedef float f32x2v __attribute__((ext_vector_type(2)));

typedef const __attribute__((address_space(1))) void* gasp_t;
typedef __attribute__((address_space(3))) void* lasp_t;
typedef __attribute__((address_space(3))) char* lcp_t;

#define LDSOFF(p) ((unsigned)(unsigned long long)(lcp_t)(void*)(p))
#define SB0() __builtin_amdgcn_sched_barrier(0)
#define WAITV(N) do { asm volatile("s_waitcnt vmcnt(" #N ")" ::: "memory"); SB0(); } while (0)
#define LGKM0() do { asm volatile("s_waitcnt lgkmcnt(0)" ::: "memory"); SB0(); } while (0)
#define BAR()   do { asm volatile("s_barrier" ::: "memory"); } while (0)
#define GL2LDS(g, l) __builtin_amdgcn_global_load_lds((gasp_t)(const void*)(g), (lasp_t)(void*)(l), 16, 0, 0)

#define RD4O(d, b, off) asm volatile("ds_read_b128 %0, %1 offset:%c2" : "=v"(d) : "v"(b), "i"(off))
#define RD2O(d, b, off) asm volatile("ds_read_b64 %0, %1 offset:%c2"  : "=v"(d) : "v"(b), "i"(off))
#define RD1O(d, b, off) asm volatile("ds_read_b32 %0, %1 offset:%c2"  : "=v"(d) : "v"(b), "i"(off))
#define WR2O(b, v2, off) asm volatile("ds_write_b64 %0, %1 offset:%c2" :: "v"(b), "v"(v2), "i"(off))
#define WR1O(b, v1, off) asm volatile("ds_write_b32 %0, %1 offset:%c2" :: "v"(b), "v"(v1), "i"(off))

#define U0(w) __builtin_bit_cast(float, (unsigned)((w) << 16))
#define U1(w) __builtin_bit_cast(float, (unsigned)((w) & 0xFFFF0000u))

#define REP8_(M)  M(0) M(1) M(2) M(3) M(4) M(5) M(6) M(7)
#define REP16_(M) REP8_(M) M(8) M(9) M(10) M(11) M(12) M(13) M(14) M(15)

// ---- staging: 8 x 1KB gload_lds per half-tile ----
#define LISSUE(SLOT, SITE) do {                                               \
  const char* _g = gL + (size_t)(SITE) * 16384;                               \
  char* _l = tW + (SLOT) * 8192;                                              \
  _Pragma("unroll") for (int i5 = 0; i5 < 8; ++i5)                            \
    GL2LDS(_g + i5 * 2048, _l + i5 * 1024);                                   \
} while (0)

#define RISSUE(SLOT, SITE) do {                                               \
  const char* _g = gR + (size_t)(SITE) * 16384;                               \
  char* _l = tW + (SLOT) * 8192;                                              \
  _Pragma("unroll") for (int i5 = 0; i5 < 8; ++i5)                            \
    GL2LDS(_g + i5 * 1024 + vrp[i5 & 1], _l + i5 * 1024);                     \
} while (0)

// ---- left compute ----
#define LT_(i) RD2O(dd[i], lb8[(i) & 7], (SLOT_) * 8192 + (i) * 128);
#define LF_(i) { const float vl = vv[(i) >> 2][(i) & 3];                      \
  a00 = fmaf(vl, U0(dd[i][0]), a00); a10 = fmaf(vl, U1(dd[i][0]), a10);       \
  a01 = fmaf(vl, U0(dd[i][1]), a01); a11 = fmaf(vl, U1(dd[i][1]), a11); }

#define LCOMP(SLOT, P, XC) do {                                               \
  constexpr int SLOT_ = (SLOT);                                               \
  u32x2 dd[16]; f32x4v vv[4]; f32x2v yo;                                      \
  RD2O(yo, yB, (P) * 256);                                                    \
  RD4O(vv[0], vqB, (P) * 256 + 0);  RD4O(vv[1], vqB, (P) * 256 + 16);         \
  RD4O(vv[2], vqB, (P) * 256 + 32); RD4O(vv[3], vqB, (P) * 256 + 48);         \
  REP16_(LT_)                                                                 \
  LGKM0();                                                                    \
  float a00 = 0.f, a10 = 0.f, a01 = 0.f, a11 = 0.f;                           \
  REP16_(LF_)                                                                 \
  a00 += __shfl_xor(a00, 16, 64); a00 += __shfl_xor(a00, 32, 64);             \
  a10 += __shfl_xor(a10, 16, 64); a10 += __shfl_xor(a10, 32, 64);             \
  a01 += __shfl_xor(a01, 16, 64); a01 += __shfl_xor(a01, 32, 64);             \
  a11 += __shfl_xor(a11, 16, 64); a11 += __shfl_xor(a11, 32, 64);             \
  if (q == 0) {                                                               \
    const float s0_ = (XC).x + (XC).y;                                        \
    f32x2v yn; yn.x = fmaf(s0_, yo.x, fmaf((XC).x, a00, (XC).y * a10));       \
    yn.y = fmaf(s0_, yo.y, fmaf((XC).x, a01, (XC).y * a11));                  \
    WR2O(yB, yn, ((P) ^ 1) * 256);                                            \
  }                                                                           \
  LGKM0();                                                                    \
} while (0)

// ---- right compute ----
#define RT_(m) RD4O(qq[m], rb8[m], (SLOT_) * 8192);
#define RV_(m) RD4O(vv[m], vhB, (P_) * 256 + (m) * 16);
#define RF_(m) {                                                              \
  { const float v_ = vv[m][0]; const unsigned W = qq[m][0];                   \
    a0 = fmaf(v_, U0(W), a0); a1 = fmaf(v_, U1(W), a1); }                     \
  { const float v_ = vv[m][1]; const unsigned W = qq[m][1];                   \
    b0 = fmaf(v_, U0(W), b0); b1 = fmaf(v_, U1(W), b1); }                     \
  { const float v_ = vv[m][2]; const unsigned W = qq[m][2];                   \
    a0 = fmaf(v_, U0(W), a0); a1 = fmaf(v_, U1(W), a1); }                     \
  { const float v_ = vv[m][3]; const unsigned W = qq[m][3];                   \
    b0 = fmaf(v_, U0(W), b0); b1 = fmaf(v_, U1(W), b1); } }

#define RCOMP(SLOT, P, XC) do {                                               \
  constexpr int SLOT_ = (SLOT); constexpr int P_ = (P);                       \
  u32x4 qq[8]; f32x4v vv[8]; float yo;                                        \
  RD1O(yo, ylB, (P) * 256);                                                   \
  REP8_(RV_)                                                                  \
  REP8_(RT_)                                                                  \
  LGKM0();                                                                    \
  float a0 = 0.f, a1 = 0.f, b0 = 0.f, b1 = 0.f;                               \
  REP8_(RF_)                                                                  \
  float s0a = a0 + b0, s1a = a1 + b1;                                         \
  s0a += __shfl_xor(s0a, 1, 64);                                              \
  s1a += __shfl_xor(s1a, 1, 64);                                              \
  if (h == 0) {                                                               \
    const float s0_ = (XC).x + (XC).y;                                        \
    const float yn = fmaf(s0_, yo, fmaf((XC).x, s0a, (XC).y * s1a));          \
    WR1O(ylB, yn, ((P) ^ 1) * 256);                                           \
  }                                                                           \
  LGKM0();                                                                    \
} while (0)

// step macros: BAR -> x-read -> WAITV -> COMP -> ISSUE
#define LSTEP(SLOT, K, XBASE, WN, ISS) do {                                   \
  BAR();                                                                      \
  f32x2v xc; RD2O(xc, XBASE, 8 * (K));                                        \
  WAITV(WN); LCOMP(SLOT, (K) & 1, xc); ISS;                                   \
} while (0)

#define RSTEP(SLOT, K, XBASE, XOFF, WN, ISS) do {                             \
  BAR();                                                                      \
  f32x2v xc; RD2O(xc, XBASE, (XOFF));                                         \
  WAITV(WN); RCOMP(SLOT, (K) & 1, xc); ISS;                                   \
} while (0)

__device__ __forceinline__ unsigned bf16rne(float f) {
    const unsigned b = __builtin_bit_cast(unsigned, f);
    return (b + 0x7FFFu + ((b >> 16) & 1u)) >> 16;
}

__global__ __launch_bounds__(256) void mps_conv_kernel(
    const float* __restrict__ cores, char* __restrict__ etab)
{
    const int p = blockIdx.x * 256 + threadIdx.x;
    const int rem = p & 4095;
    const int l = rem >> 6, r = rem & 63;
    const float2 c = ((const float2*)cores)[p];
    const float sub = (l == r) ? 1.0f : 0.0f;
    ((unsigned*)etab)[p] = bf16rne(c.x - sub) | (bf16rne(c.y - sub) << 16);
}

__global__ __launch_bounds__(128, 1) void mps_chain_kernel(
    const float* __restrict__ x,      // [B][S][2]
    const char* __restrict__ etab,    // bf16 E table
    float* __restrict__ wsv)          // [B][2][64]
{
    __shared__ __align__(16) char tiles[2][6][8192];   // 96KB: [wave][slot]
    __shared__ __align__(16) float vbuf[2][ND];        // ping-pong vector
    __shared__ __align__(16) float xlds[NS * 2];

    const int bid   = blockIdx.x;
    const int batch = bid >> 1;
    const int right = bid & 1;
    const int tid   = threadIdx.x;
    const int w     = tid >> 6;
    const int lane  = tid & 63;

    for (int i = tid; i < 98; i += 128)
        ((float4*)xlds)[i] = ((const float4*)(x + batch * (NS * 2)))[i];
    if (tid < 64) vbuf[0][tid] = (tid == 0) ? 1.0f : 0.0f;
    __syncthreads();   // drains prologue; asm counters start at 0

    char* tW = (char*)tiles + w * 49152;
    const unsigned tB = LDSOFF(tiles) + (unsigned)(w * 49152);
    const unsigned vB = LDSOFF(vbuf);
    const unsigned xB = LDSOFF(xlds);

    if (!right) {
        const int q = lane >> 4, t = lane & 15;
        unsigned lb8[8];
        #pragma unroll
        for (int c = 0; c < 8; ++c)
            lb8[c] = tB + (unsigned)(q * 2048 + ((8 * t) ^ (c << 4)));
        const unsigned vqB = vB + (unsigned)(q * 64);
        const unsigned yB  = vB + (unsigned)(w * 128 + t * 8);
        const char* gL = etab + (lane >> 3) * 256 + w * 128
                              + (((lane & 7) ^ (lane >> 3)) << 4);
        LISSUE(0, 0); LISSUE(1, 1); LISSUE(2, 2);
        LISSUE(3, 3); LISSUE(4, 4); LISSUE(5, 5);
        for (int s = 0; s < 90; s += 6) {
            const unsigned xs = xB + 8u * (unsigned)s;
            LSTEP(0, 0, xs, 40, LISSUE(0, s + 6));
            LSTEP(1, 1, xs, 40, LISSUE(1, s + 7));
            LSTEP(2, 2, xs, 40, LISSUE(2, s + 8));
            LSTEP(3, 3, xs, 40, LISSUE(3, s + 9));
            LSTEP(4, 4, xs, 40, LISSUE(4, s + 10));
            LSTEP(5, 5, xs, 40, LISSUE(5, s + 11));
        }
        {   // steps 90..97 (sites 90..97), parity = step&1, slot = step%6
            const unsigned xs = xB + 8u * 90u;
            LSTEP(0, 0, xs, 40, LISSUE(0, 96));
            LSTEP(1, 1, xs, 40, LISSUE(1, 97));
            LSTEP(2, 2, xs, 40, );
            LSTEP(3, 3, xs, 32, );
            LSTEP(4, 4, xs, 24, );
            LSTEP(5, 5, xs, 16, );
            LSTEP(0, 6, xs, 8,  );
            LSTEP(1, 7, xs, 0,  );
        }
    } else {
        const int l_loc = lane >> 1, h = lane & 1, s7 = l_loc & 7;
        unsigned rb8[8];
        #pragma unroll
        for (int m = 0; m < 8; ++m)
            rb8[m] = tB + (unsigned)(l_loc * 256 + h * 128 + ((m ^ s7) << 4));
        const unsigned vhB = vB + (unsigned)(h * 128);
        const unsigned ylB = vB + (unsigned)((32 * w + l_loc) * 4);
        unsigned vrp[2];
        #pragma unroll
        for (int p5 = 0; p5 < 2; ++p5)
            vrp[p5] = (unsigned)((lane >> 4) * 256
                      + (((lane & 15) ^ (4 * p5 + (lane >> 4))) << 4));
        const char* gR = etab + w * 8192;
        RISSUE(0, 195); RISSUE(1, 194); RISSUE(2, 193);
        RISSUE(3, 192); RISSUE(4, 191); RISSUE(5, 190);
        for (int s = 0; s < 90; s += 6) {
            // sites 195-s-k; x base at lowest site of this iter = 190-s
            const unsigned xs = xB + 8u * (unsigned)(190 - s);
            RSTEP(0, 0, xs, 8 * 5, 40, RISSUE(0, 189 - s));
            RSTEP(1, 1, xs, 8 * 4, 40, RISSUE(1, 188 - s));
            RSTEP(2, 2, xs, 8 * 3, 40, RISSUE(2, 187 - s));
            RSTEP(3, 3, xs, 8 * 2, 40, RISSUE(3, 186 - s));
            RSTEP(4, 4, xs, 8 * 1, 40, RISSUE(4, 185 - s));
            RSTEP(5, 5, xs, 8 * 0, 40, RISSUE(5, 184 - s));
        }
        {   // steps 90..97: sites 105..98; x base at site 98
            const unsigned xs = xB + 8u * 98u;
            RSTEP(0, 0, xs, 8 * 7, 40, RISSUE(0, 99));
            RSTEP(1, 1, xs, 8 * 6, 40, RISSUE(1, 98));
            RSTEP(2, 2, xs, 8 * 5, 40, );
            RSTEP(3, 3, xs, 8 * 4, 32, );
            RSTEP(4, 4, xs, 8 * 3, 24, );
            RSTEP(5, 5, xs, 8 * 2, 16, );
            RSTEP(0, 6, xs, 8 * 1, 8,  );
            RSTEP(1, 7, xs, 8 * 0, 0,  );
        }
    }
    BAR();
    if (tid < 64) {
        float fin; RD1O(fin, vB + (unsigned)(tid * 4), 0); LGKM0();
        wsv[batch * 128 + right * 64 + tid] = fin;
    }
}

__global__ __launch_bounds__(128) void mps_out_kernel(
    const float* __restrict__ wsv,    // [B][2][64]
    const float* __restrict__ oc,     // [O][D][D]
    float* __restrict__ out)          // [B][O]
{
    __shared__ __align__(16) float lsh[ND];
    __shared__ __align__(16) float rsh[ND];
    const int b    = blockIdx.x;
    const int tid  = threadIdx.x;
    const int wave = tid >> 6;
    const int lane = tid & 63;
    if (wave == 0) lsh[lane] = wsv[b * 128 + lane];
    else           rsh[lane] = wsv[b * 128 + 64 + lane];
    __syncthreads();

    #pragma unroll
    for (int oo = 0; oo < 5; ++oo) {
        const int o = wave * 5 + oo;
        const float* ocp = oc + o * (ND * ND) + lane * ND;
        float acc = 0.f;
        #pragma unroll
        for (int t = 0; t < ND; t += 4) {
            const float4 r4 = *(const float4*)(rsh + t);
            const float4 c4 = *(const float4*)(ocp + t);
            acc = fmaf(c4.x, r4.x, acc);
            acc = fmaf(c4.y, r4.y, acc);
            acc = fmaf(c4.z, r4.z, acc);
            acc = fmaf(c4.w, r4.w, acc);
        }
        float p = lsh[lane] * acc;
        #pragma unroll
        for (int off = 32; off > 0; off >>= 1) p += __shfl_xor(p, off, 64);
        if (lane == 0) out[b * NO + o] = p;
    }
}
} // namespace

extern "C" void kernel_launch(void* const* d_in, const int* in_sizes, int n_in,
                              void* d_out, int out_size, void* d_ws, size_t ws_size,
                              hipStream_t stream) {
    const float* x     = (const float*)d_in[0];
    const float* cores = (const float*)d_in[1];
    const float* ocp   = (const float*)d_in[2];
    float* out = (float*)d_out;
    char*  etab = (char*)d_ws;
    float* wsv  = (float*)((char*)d_ws + EBYTES);
    hipLaunchKernelGGL(mps_conv_kernel,  dim3(EPAIRS / 256), dim3(256), 0, stream, cores, etab);
    hipLaunchKernelGGL(mps_chain_kernel, dim3(2 * NB), dim3(128), 0, stream, x, etab, wsv);
    hipLaunchKernelGGL(mps_out_kernel,   dim3(NB),     dim3(128), 0, stream, wsv, ocp, out);
}